// Round 2
// baseline (1248.907 us; speedup 1.0000x reference)
//
#include <hip/hip_runtime.h>
#include <hip/hip_bf16.h>

// Titans memory module, MI355X fused implementation.
// Pass 1 (titans_main): streams k,v once; computes retrieved (fp32, exact),
//   loss partials, k column-sum partials, and grad = diff^T @ k partials via
//   bf16 MFMA (grad ~3e-5 pre-clamp; bf16 error ~1e-9 in new_S -> safe).
// Pass 2 (titans_gradreduce): reduces per-block grad partials, scales+clamps.
// Pass 3 (titans_finalize): gates, new_S, new_W, norm clip; tiny single block.
//
// LDS swizzle for kt (k^T tile, word = c*64 + ((i>>2 ^ g(c))<<2) + (i&3),
// g(c) = (c ^ (c>>2)) & 15) gives <=2-way (free) bank aliasing on ALL four
// access patterns: staging write, retrieve column read, MFMA B b128 read.
// The MFMA uses a slot-permutation pairing: A slot (sigma^j from dt) and
// B slot (sigma^g(c) from kt) both hold element i = 4*sigma + t, so the
// hardware's positional A/B slot pairing sums the correct 32 products
// independent of the actual hardware k-slot map.

typedef float  v4f  __attribute__((ext_vector_type(4)));
typedef __bf16 v8bf __attribute__((ext_vector_type(8)));

union BfPack { unsigned int u[4]; v8bf v; };

__device__ __forceinline__ int kt_g(int c) { return (c ^ (c >> 2)) & 15; }

__global__ __launch_bounds__(256, 4)
void titans_main(const float* __restrict__ k,
                 const float* __restrict__ v,
                 const float* __restrict__ W,
                 float* __restrict__ out_retr,
                 float* __restrict__ gpart,   // [grid][4096]
                 float* __restrict__ kpart,   // [grid][64]
                 float* __restrict__ lpart,   // [grid]
                 int nrows)
{
    // kt[c][i]: c = k-column 0..63, i = chunk-row 0..63 (fp32, swizzled above)
    __shared__ __align__(16) float kt[4096];
    // dt: per-wave diff tile bf16, dt[w][ j*64 + ((i>>2 ^ j)<<2) + (i&3) ]
    __shared__ __align__(16) unsigned short dt[4][1024];
    __shared__ float ksum_lds[64];
    __shared__ float loss_lds;

    const int tid = threadIdx.x;
    const int w   = tid >> 6;    // wave 0..3 : owns output columns w*16..w*16+15
    const int l   = tid & 63;    // lane
    const int l15 = l & 15;
    const int kg  = l >> 4;      // 0..3
    const int p   = l >> 2;      // i>>2 when lane==row
    const int q   = l & 3;       // i&3  when lane==row

    if (tid < 64) ksum_lds[tid] = 0.f;
    if (tid == 0) loss_lds = 0.f;

    float ksum4[4] = {0.f, 0.f, 0.f, 0.f};
    float lossacc  = 0.f;
    v4f gacc[4];
    #pragma unroll
    for (int nt = 0; nt < 4; ++nt) gacc[nt] = (v4f){0.f, 0.f, 0.f, 0.f};

    const int nchunks = nrows >> 6;

    // staging-write column ids + swizzles (depend only on e)
    int cwr[4], gwr[4];
    #pragma unroll
    for (int e = 0; e < 4; ++e) { cwr[e] = l15 * 4 + e; gwr[e] = kt_g(cwr[e]); }

    for (int ch = blockIdx.x; ch < nchunks; ch += gridDim.x) {
        const long R0 = (long)ch << 6;

        // ---- stage: coalesced float4 loads (wave w: chunk rows w*16..w*16+15)
        float4 kv[4];
        #pragma unroll
        for (int g = 0; g < 4; ++g) {
            const int rl = w * 16 + g * 4 + kg;          // chunk-local row
            kv[g] = *(const float4*)(k + (R0 + rl) * 64 + l15 * 4);
        }
        #pragma unroll
        for (int g = 0; g < 4; ++g) {                    // k column-sum partials
            ksum4[0] += kv[g].x; ksum4[1] += kv[g].y;
            ksum4[2] += kv[g].z; ksum4[3] += kv[g].w;
        }

        __syncthreads();  // A: previous chunk's kt readers are done
        #pragma unroll
        for (int g = 0; g < 4; ++g) {
            const int rh = w * 4 + g;                    // i>>2 (wave-uniform); i&3 == kg
            const float vals[4] = {kv[g].x, kv[g].y, kv[g].z, kv[g].w};
            #pragma unroll
            for (int e = 0; e < 4; ++e)
                kt[cwr[e] * 64 + ((rh ^ gwr[e]) << 2) + kg] = vals[e];
        }
        __syncthreads();  // B: kt ready for all waves

        // ---- retrieve: lane = chunk row i (=l), wave w computes cols w*16..+15.
        // W operand is wave-uniform -> readfirstlane forces s_load (scalar pipe).
        float acc[16];
        #pragma unroll
        for (int j = 0; j < 16; ++j) acc[j] = 0.f;

        #pragma unroll
        for (int kkb = 0; kkb < 4; ++kkb) {
            float k16[16];
            #pragma unroll
            for (int e = 0; e < 16; ++e) {
                const int kk = kkb * 16 + e;
                k16[e] = kt[kk * 64 + ((p ^ kt_g(kk)) << 2) + q];
            }
            #pragma unroll
            for (int j = 0; j < 16; ++j) {
                const int wrow = __builtin_amdgcn_readfirstlane(w * 16 + j);
                const float* wr = W + wrow * 64 + kkb * 16;
                #pragma unroll
                for (int e = 0; e < 16; ++e)
                    acc[j] = fmaf(k16[e], wr[e], acc[j]);
            }
        }

        // ---- diff, loss, store retrieved, stash diff as bf16 for MFMA
        const long rg = R0 + l;
        #pragma unroll
        for (int qq = 0; qq < 4; ++qq) {
            const long base = rg * 64 + w * 16 + qq * 4;
            const float4 vv = *(const float4*)(v + base);
            float4 rr;
            rr.x = acc[qq*4+0]; rr.y = acc[qq*4+1]; rr.z = acc[qq*4+2]; rr.w = acc[qq*4+3];
            *(float4*)(out_retr + base) = rr;
            const float dd[4] = {rr.x - vv.x, rr.y - vv.y, rr.z - vv.z, rr.w - vv.w};
            lossacc = fmaf(dd[0], dd[0], lossacc);
            lossacc = fmaf(dd[1], dd[1], lossacc);
            lossacc = fmaf(dd[2], dd[2], lossacc);
            lossacc = fmaf(dd[3], dd[3], lossacc);
            #pragma unroll
            for (int e2 = 0; e2 < 4; ++e2) {
                const int j = qq * 4 + e2;
                const __bf16 hb = (__bf16)dd[e2];
                dt[w][j * 64 + ((p ^ j) << 2) + q] = __builtin_bit_cast(unsigned short, hb);
            }
        }

        // ---- grad accumulation: grad[jv][jk] += sum_i diff[i][jv] * k[i][jk]
        // mfma_f32_16x16x32_bf16: A = diff^T (dt, swizzle j), B = k (kt, swizzle g(c)).
        #pragma unroll
        for (int kt_ = 0; kt_ < 2; ++kt_) {
            const int sig0 = 8 * kt_ + kg;       // i>>2 for slots 0..3
            const int sig1 = 8 * kt_ + 4 + kg;   // i>>2 for slots 4..7
            BfPack ap;
            {
                const int a0 = sig0 ^ l15, a1 = sig1 ^ l15;
                const uint2 lo = *(const uint2*)(&dt[w][l15 * 64 + (a0 << 2)]);
                const uint2 hi = *(const uint2*)(&dt[w][l15 * 64 + (a1 << 2)]);
                ap.u[0] = lo.x; ap.u[1] = lo.y; ap.u[2] = hi.x; ap.u[3] = hi.y;
            }
            #pragma unroll
            for (int nt = 0; nt < 4; ++nt) {
                const int c  = nt * 16 + l15;
                const int gc = kt_g(c);
                const float4 b0 = *(const float4*)(&kt[c * 64 + ((sig0 ^ gc) << 2)]);
                const float4 b1 = *(const float4*)(&kt[c * 64 + ((sig1 ^ gc) << 2)]);
                v8bf bv;
                bv[0] = (__bf16)b0.x; bv[1] = (__bf16)b0.y;
                bv[2] = (__bf16)b0.z; bv[3] = (__bf16)b0.w;
                bv[4] = (__bf16)b1.x; bv[5] = (__bf16)b1.y;
                bv[6] = (__bf16)b1.z; bv[7] = (__bf16)b1.w;
                gacc[nt] = __builtin_amdgcn_mfma_f32_16x16x32_bf16(ap.v, bv, gacc[nt], 0, 0, 0);
            }
        }
    }

    // ---- per-block partial outputs
    // D layout (m89-verified): col = lane&15, row = (lane>>4)*4 + reg
    #pragma unroll
    for (int nt = 0; nt < 4; ++nt) {
        #pragma unroll
        for (int r = 0; r < 4; ++r) {
            const int jv = w * 16 + kg * 4 + r;
            gpart[(long)blockIdx.x * 4096 + jv * 64 + nt * 16 + l15] = gacc[nt][r];
        }
    }

    #pragma unroll
    for (int e = 0; e < 4; ++e) atomicAdd(&ksum_lds[l15 * 4 + e], ksum4[e]);
    atomicAdd(&loss_lds, lossacc);
    __syncthreads();
    if (tid < 64)  kpart[blockIdx.x * 64 + tid] = ksum_lds[tid];
    if (tid == 0)  lpart[blockIdx.x] = loss_lds;
}

__global__ void titans_gradreduce(const float* __restrict__ gpart,
                                  float* __restrict__ gclamp,
                                  float scale2, int nblocks)
{
    const int t = blockIdx.x * 256 + threadIdx.x;   // 16 blocks x 256 = 4096
    float s = 0.f;
    for (int pb = 0; pb < nblocks; ++pb) s += gpart[(long)pb * 4096 + t];
    s *= scale2;
    s = fminf(1.f, fmaxf(-1.f, s));
    gclamp[t] = s;
}

__global__ void titans_finalize(const float* __restrict__ W,
                                const float* __restrict__ gw,
                                const float* __restrict__ gb,
                                const float* __restrict__ S,
                                const float* __restrict__ kpart,
                                const float* __restrict__ lpart,
                                const float* __restrict__ gclamp,
                                float* __restrict__ out,
                                float* __restrict__ rwbuf,
                                int nrows, int nblocks)
{
    __shared__ float  red[256];
    __shared__ double dred[256];
    __shared__ float  kmean[64];
    __shared__ float  gates_s[3];
    __shared__ float  scale_s;

    const int  tid   = threadIdx.x;
    const long NR    = (long)nrows * 64;
    const long LOSS_OFF  = NR;
    const long NW_OFF    = NR + 1;
    const long NS_OFF    = NR + 1 + 4096;
    const long GATES_OFF = NR + 1 + 8192;

    // k column means
    const int c = tid & 63, s4 = tid >> 6;
    float ks = 0.f;
    for (int pb = s4; pb < nblocks; pb += 4) ks += kpart[pb * 64 + c];
    red[tid] = ks;
    __syncthreads();
    if (tid < 64)
        kmean[tid] = (red[tid] + red[tid + 64] + red[tid + 128] + red[tid + 192]) / (float)nrows;

    // loss (double-accumulate per-block partials)
    double ls = 0.0;
    for (int pb = tid; pb < nblocks; pb += 256) ls += (double)lpart[pb];
    dred[tid] = ls;
    __syncthreads();
    if (tid == 0) {
        double t = 0.0;
        for (int i = 0; i < 256; ++i) t += dred[i];
        out[LOSS_OFF] = (float)(t / ((double)nrows * 64.0));
    }
    if (tid < 3) {
        float x = gb[tid];
        for (int cc = 0; cc < 64; ++cc) x = fmaf(kmean[cc], gw[tid * 64 + cc], x);
        const float g = 1.f / (1.f + expf(-x));
        gates_s[tid] = g;
        out[GATES_OFF + tid] = g;
    }
    __syncthreads();

    const float alpha = gates_s[0], eta = gates_s[1], theta = gates_s[2];
    double na = 0.0;
    for (int e = tid; e < 4096; e += 256) {
        const float g  = gclamp[e];
        const float ns = eta * S[e] - 0.01f * theta * g;
        out[NS_OFF + e] = ns;
        const float rw = (1.f - alpha) * W[e] + ns;
        rwbuf[e] = rw;
        na += (double)rw * (double)rw;
    }
    dred[tid] = na;
    __syncthreads();
    if (tid == 0) {
        double t = 0.0;
        for (int i = 0; i < 256; ++i) t += dred[i];
        const float wn = (float)sqrt(t);
        scale_s = (wn > 10.0f) ? (10.0f / (wn + 1e-8f)) : 1.0f;
    }
    __syncthreads();
    const float sc = scale_s;
    for (int e = tid; e < 4096; e += 256) out[NW_OFF + e] = rwbuf[e] * sc;
}

extern "C" void kernel_launch(void* const* d_in, const int* in_sizes, int n_in,
                              void* d_out, int out_size, void* d_ws, size_t ws_size,
                              hipStream_t stream)
{
    const float* k  = (const float*)d_in[0];
    const float* v  = (const float*)d_in[1];
    const float* W  = (const float*)d_in[2];
    const float* gw = (const float*)d_in[3];
    const float* gb = (const float*)d_in[4];
    const float* S  = (const float*)d_in[5];
    float* out = (float*)d_out;
    const int nrows = in_sizes[0] / 64;

    // grid sized to workspace: per block 4096 (gpart) + 64 (kpart) + 1 (lpart)
    // floats, plus 8192 floats fixed (gclamp + rwbuf).
    long avail = (long)(ws_size / sizeof(float)) - 8192;
    int grid1 = (int)(avail / 4161);
    if (grid1 > 1024) grid1 = 1024;
    if (grid1 < 1)    grid1 = 1;    // degenerate ws; still correct

    float* ws     = (float*)d_ws;
    float* gpart  = ws;                          // grid1*4096
    float* kpart  = ws + (long)grid1 * 4096;     // grid1*64
    float* lpart  = kpart + (long)grid1 * 64;    // grid1
    float* gclamp = lpart + grid1;               // 4096
    float* rwbuf  = gclamp + 4096;               // 4096

    titans_main<<<grid1, 256, 0, stream>>>(k, v, W, out, gpart, kpart, lpart, nrows);
    titans_gradreduce<<<16, 256, 0, stream>>>(gpart, gclamp,
                                              2.0f / (float)((long)nrows * 64), grid1);
    titans_finalize<<<1, 256, 0, stream>>>(W, gw, gb, S, kpart, lpart, gclamp,
                                           out, rwbuf, nrows, grid1);
}